// Round 13
// baseline (80.849 us; speedup 1.0000x reference)
//
#include <hip/hip_runtime.h>

// Partial Radon transform:
//  x: (4, 1, 256, 256) f32 -> out: (4, 5, 256, 180) f32
//
// Round 13 = two-pass half-image staging, rebuilt WITHOUT the R6/R7 bug.
// R6/R7 failed because quarters were stride-4 PHASES with wave-dependent
// start (hs0 = max(LO, wlo)): threads sharing an output w live in different
// waves with different wlo -> phase collision -> double/zero coverage.
// Here quarters are CONTIGUOUS sub-ranges (proven R5/R11 structure); each
// thread's h-set is its own contiguous window-clipped range. Coverage holds:
// wave window superset of thread window; out-of-window h have m=false.
//  - pair-cell LDS, 131 local rows x 131 dw = 68,644 B -> 2 blocks/CU
//    -> 8 waves/SIMD (launch_bounds(1024,8); VGPR must stay <=64).
//  - split at padded slow 130; m=(sl<130)==(pass==0) bitwise-identical.
//  - per-pass zero-fill disjoint from staging (one barrier per pass).
// Unchanged from R11: XCD swizzle, alignbit/fract/packed-f16 lerp sample,
// unroll 8, reduction epilogue.

constexpr int WIDTH  = 256;
constexpr int NANG   = 180;
constexpr int NBATCH = 4;
constexpr int NS     = 5;
constexpr int CSTR   = 131;   // dword cells per slow-row; 131%32=3
constexpr int LROWS  = 131;   // local slow-rows per pass
constexpr int SPLIT  = 130;   // padded-slow split boundary

typedef _Float16 h2 __attribute__((ext_vector_type(2)));

#if __has_builtin(__builtin_amdgcn_fractf)
#define FRACT(x) __builtin_amdgcn_fractf(x)
#else
#define FRACT(x) ((x) - floorf(x))
#endif

__device__ inline unsigned pack2_f16(float a, float b) {
    _Float16 ha = (_Float16)a, hb = (_Float16)b;
    unsigned short ua = __builtin_bit_cast(unsigned short, ha);
    unsigned short ub = __builtin_bit_cast(unsigned short, hb);
    return (unsigned)ua | ((unsigned)ub << 16);
}

__global__ __launch_bounds__(1024, 8) void radon_kernel(const float* __restrict__ x,
                                                        float* __restrict__ out) {
    __shared__ unsigned cells[LROWS * CSTR];   // 68,644 B

    const int bid = blockIdx.x;
    const int lin = (bid & 7) * 90 + (bid >> 3);   // XCD swizzle, bijective
    const int n = lin / NANG;
    const int a = lin - n * NANG;
    const int t = threadIdx.x;
    const int w = t & 255;
    const int quarter = t >> 8;          // contiguous 64-h range per quarter

    const float* __restrict__ img = x + (size_t)n * WIDTH * WIDTH;

    const float theta = (float)a * 0.017453292519943295f;
    float s, c;
    sincosf(theta, &s, &c);
    const bool transp = (c * c > s * s);

    const float bw  = ((float)w + 0.5f) * (2.0f / WIDTH) - 1.0f;
    const float bh0 = 0.5f * (2.0f / WIDTH) - 1.0f;
    const float gx0 = c * bw + s * bh0;
    const float gy0 = -s * bw + c * bh0;
    const float ix0 = ((gx0 + 1.0f) * (float)WIDTH - 1.0f) * 0.5f;
    const float iy0 = ((gy0 + 1.0f) * (float)WIDTH - 1.0f) * 0.5f;

    const float fast0 = (transp ? iy0 : ix0) + 2.0f;
    const float slow0 = (transp ? ix0 : iy0) + 2.0f;
    const float dfast = transp ? c : s;
    const float dslow = transp ? s : c;

    float r0 = 0.f, r1 = 0.f, r2 = 0.f, r3 = 0.f, r4 = 0.f;

    for (int pass = 0; pass < 2; ++pass) {
        // ---- zero-fill (disjoint from staging) ----
        // cols j = 0,129,130 every local row (staging writes j 1..128 only)
        if (t < LROWS) {
            const int b = t * CSTR;
            cells[b] = 0u; cells[b + 129] = 0u; cells[b + 130] = 0u;
        }
        if (pass == 0) {
            for (int i = t; i < 2 * CSTR; i += 1024) cells[i] = 0u;          // rows 0,1
        } else {
            for (int i = t; i < 3 * CSTR; i += 1024) cells[128 * CSTR + i] = 0u; // rows 128,129,130
        }

        // ---- stage this pass's half ----
        // pass 0: orig slow 0..128 -> local 2..130 ; pass 1: orig 128..255 -> local 0..127
        if (!transp) {
            const int nrows = pass ? 128 : 129;
            const int glo   = pass ? 128 : 0;
            for (int d = t; d < nrows * 128; d += 1024) {
                const int ys = d >> 7, xd = d & 127;
                const float2 v = ((const float2*)img)[(glo + ys) * 128 + xd];
                const int loc = pass ? ys : (ys + 2);
                cells[loc * CSTR + xd + 1] = pack2_f16(v.x, v.y);
            }
        } else {
            // slow = x: lane<->x (coalesced rows); cell c = orig y pair
            const bool part = pass ? (w >= 128) : (w <= 128);
            if (part) {
                const int loc = pass ? (w - 128) : (w + 2);
                for (int yp = quarter; yp < 128; yp += 4) {
                    const float v0 = img[(2 * yp) * WIDTH + w];
                    const float v1 = img[(2 * yp + 1) * WIDTH + w];
                    cells[loc * CSTR + yp + 1] = pack2_f16(v0, v1);
                }
            }
        }
        __syncthreads();

        // ---- per-thread h-window (slack 3; predicate m is exact) ----
        const float hstar = (130.0f - slow0) / dslow;
        const float hcl = fminf(fmaxf(hstar, -10000.0f), 10000.0f);
        int lo, hi;
        if (dslow > 0.0f) {
            if (pass == 0) { lo = 0;            hi = (int)hcl + 3; }
            else           { lo = (int)hcl - 3; hi = 256; }
        } else if (dslow < 0.0f) {
            if (pass == 0) { lo = (int)hcl - 3; hi = 256; }
            else           { lo = 0;            hi = (int)hcl + 3; }
        } else { lo = 0; hi = 256; }
        lo = max(lo, 0); hi = min(hi, 256);

        int wlo = lo, whi = hi;
        for (int off = 1; off < 64; off <<= 1) {
            wlo = min(wlo, __shfl_xor(wlo, off));
            whi = max(whi, __shfl_xor(whi, off));
        }
        wlo = __builtin_amdgcn_readfirstlane(wlo);   // scalar loop bounds
        whi = __builtin_amdgcn_readfirstlane(whi);

        auto sample = [&](int h) -> float {
            const float hf = (float)h;
            float fa = fmaf(hf, dfast, fast0);
            float sl = fmaf(hf, dslow, slow0);
            fa = __builtin_amdgcn_fmed3f(fa, 1.0f, 258.0f);
            sl = __builtin_amdgcn_fmed3f(sl, 1.0f, 258.0f);
            const bool m = (sl < 130.0f) == (pass == 0);   // exact partition
            const int fi = (int)fa, si = (int)sl;          // trunc == floor
            const float wf = FRACT(fa);
            const float ws = FRACT(sl);
            const int j = fi >> 1;
            const int sh = (fi & 1) << 4;
            int siL = si - SPLIT * pass;
            siL = min(max(siL, 0), 129);   // m-true reads exact; junk discarded
            const unsigned* rowA = &cells[__mul24(siL, CSTR) + j];
            const unsigned loA = rowA[0],    hiA = rowA[1];
            const unsigned loB = rowA[CSTR], hiB = rowA[CSTR + 1];
            const unsigned pa = __builtin_amdgcn_alignbit(hiA, loA, sh);
            const unsigned pb = __builtin_amdgcn_alignbit(hiB, loB, sh);
            const h2 va = __builtin_bit_cast(h2, pa);
            const h2 vb = __builtin_bit_cast(h2, pb);
            const _Float16 wsh = (_Float16)ws;
            const h2 ws2 = {wsh, wsh};
            const h2 col = (vb - va) * ws2 + va;    // packed lerp, slow axis
            const float c0 = (float)col.x;
            const float c1 = (float)col.y;
            const float val = fmaf(wf, c1 - c0, c0);
            return m ? val : 0.0f;
        };

        // Ring bands, contiguous per quarter (NO phase interleave):
        //  r4:[0,32)u[224,256)  r3:[32,64)u[192,224)
        //  r2:[64,96)u[160,192) r1:[96,127)u[129,160) r0:{127,128}
        #define SEG(LO, HI, R) { \
            const int hs = max(LO, wlo), he = min(HI, whi); \
            _Pragma("unroll 8") \
            for (int h = hs; h < he; ++h) R += sample(h); }
        if (quarter == 0) {
            SEG(0, 32, r4)
            SEG(32, 64, r3)
        } else if (quarter == 1) {
            SEG(64, 96, r2)
            SEG(96, 127, r1)
            if (127 >= wlo && 127 < whi) r0 += sample(127);
        } else if (quarter == 2) {
            if (128 >= wlo && 128 < whi) r0 += sample(128);
            SEG(129, 160, r1)
            SEG(160, 192, r2)
        } else {
            SEG(192, 224, r3)
            SEG(224, 256, r4)
        }
        #undef SEG

        __syncthreads();   // sampling done before next pass overwrites LDS
    }

    // ---- cross-quarter reduction via LDS reuse ----
    float* red = (float*)cells;            // 1024*5 floats = 20,480 B
    const int base = t * NS;
    red[base + 0] = r0;
    red[base + 1] = r1;
    red[base + 2] = r2;
    red[base + 3] = r3;
    red[base + 4] = r4;
    __syncthreads();

    if (t < 256) {
        const int b0 = t * NS, b1 = b0 + 256 * NS, b2 = b0 + 512 * NS, b3 = b0 + 768 * NS;
        const float s0 = (red[b0+0] + red[b1+0]) + (red[b2+0] + red[b3+0]);
        const float s1 = (red[b0+1] + red[b1+1]) + (red[b2+1] + red[b3+1]);
        const float s2 = (red[b0+2] + red[b1+2]) + (red[b2+2] + red[b3+2]);
        const float s3 = (red[b0+3] + red[b1+3]) + (red[b2+3] + red[b3+3]);
        const float s4 = (red[b0+4] + red[b1+4]) + (red[b2+4] + red[b3+4]);

        float* o = out + (((size_t)n * NS) * WIDTH + (size_t)t) * NANG + (size_t)a;
        float cum = s0;
        o[0]                          = cum * (1.0f / 2.0f);
        cum += s1;
        o[(size_t)1 * WIDTH * NANG]   = cum * (1.0f / 64.0f);
        cum += s2;
        o[(size_t)2 * WIDTH * NANG]   = cum * (1.0f / 128.0f);
        cum += s3;
        o[(size_t)3 * WIDTH * NANG]   = cum * (1.0f / 192.0f);
        cum += s4;
        o[(size_t)4 * WIDTH * NANG]   = cum * (1.0f / 256.0f);
    }
}

extern "C" void kernel_launch(void* const* d_in, const int* in_sizes, int n_in,
                              void* d_out, int out_size, void* d_ws, size_t ws_size,
                              hipStream_t stream) {
    const float* x = (const float*)d_in[0];
    float* out = (float*)d_out;
    radon_kernel<<<NBATCH * NANG, 1024, 0, stream>>>(x, out);
}